// Round 5
// baseline (22.275 us; speedup 1.0000x reference)
//
#include <hip/hip_runtime.h>
#include <hip/hip_bf16.h>

// DIAGNOSTIC ROUND: same kernel as round 4, dispatched 4x back-to-back
// (idempotent: each dispatch writes identical values). Graph capture
// serializes stream-ordered dispatches, so
//   dur_us ~= fixed_overhead + 4*work  (dispatches 2-4 run L3-hot).
// Marginal slope isolates true per-dispatch work time vs launch overhead.
//
// ConceptEmbedding: out[b,s,:] = table[token_type[b,s]][concept[b,s], :],
// tables 1=proc, 2=med, 3=chart; zeros otherwise. B=16,S=2048,E=128,V=100000.

typedef float f32x4 __attribute__((ext_vector_type(4)));

__global__ __launch_bounds__(256) void concept_emb_kernel(
    const float* __restrict__ proc,
    const float* __restrict__ med,
    const float* __restrict__ chart,
    const int*   __restrict__ concept,
    const int*   __restrict__ ttype,
    float*       __restrict__ out,
    int ngroups) {          // ngroups = npos/2
  int gid = blockIdx.x * blockDim.x + threadIdx.x;
  int j = gid & 31;         // float4 index within the 128-float row
  int g = gid >> 5;
  if (g >= ngroups) return;
  int pos0 = g * 2;
  int pos1 = pos0 + 1;

  int t0 = ttype[pos0];
  int t1 = ttype[pos1];
  int c0 = concept[pos0];
  int c1 = concept[pos1];

  const float* tab0 = (t0 == 2) ? med : (t0 == 3) ? chart : proc;
  const float* tab1 = (t1 == 2) ? med : (t1 == 3) ? chart : proc;

  f32x4 v0 = {0.f, 0.f, 0.f, 0.f};
  f32x4 v1 = {0.f, 0.f, 0.f, 0.f};
  if (t0 != 0) v0 = *reinterpret_cast<const f32x4*>(tab0 + (size_t)c0 * 128 + j * 4);
  if (t1 != 0) v1 = *reinterpret_cast<const f32x4*>(tab1 + (size_t)c1 * 128 + j * 4);

  f32x4* o0 = reinterpret_cast<f32x4*>(out + (size_t)pos0 * 128 + j * 4);
  f32x4* o1 = reinterpret_cast<f32x4*>(out + (size_t)pos1 * 128 + j * 4);
  __builtin_nontemporal_store(v0, o0);
  __builtin_nontemporal_store(v1, o1);
}

extern "C" void kernel_launch(void* const* d_in, const int* in_sizes, int n_in,
                              void* d_out, int out_size, void* d_ws, size_t ws_size,
                              hipStream_t stream) {
  const float* proc    = (const float*)d_in[0];
  const float* med     = (const float*)d_in[1];
  const float* chart   = (const float*)d_in[2];
  const int*   concept = (const int*)d_in[3];
  const int*   ttype   = (const int*)d_in[4];
  float*       out     = (float*)d_out;

  const int npos    = in_sizes[3];        // B*S = 32768 (even)
  const int ngroups = npos / 2;           // 16384
  const int threads = 256;
  const long long total = (long long)ngroups * 32;   // 524288 threads
  const int blocks = (int)((total + threads - 1) / threads);  // 2048

  // 4 identical idempotent dispatches: slope = per-dispatch work time.
  for (int rep = 0; rep < 4; ++rep) {
    concept_emb_kernel<<<blocks, threads, 0, stream>>>(
        proc, med, chart, concept, ttype, out, ngroups);
  }
}

// Round 6
// 10.207 us; speedup vs baseline: 2.1824x; 2.1824x over previous
//
#include <hip/hip_runtime.h>
#include <hip/hip_bf16.h>

// ConceptEmbedding: out[b,s,:] = table[token_type[b,s]][concept[b,s], :] where
// table 1=proc, 2=med, 3=chart; zeros otherwise (token_type in [0,4)).
// B=16, S=2048, E=128, V=100000. Output f32 [B,S,E].
//
// FINAL KERNEL (round-4 structure). Roofline analysis (round-5 4x-dispatch
// probe): dur = 6.3us fixed graph-replay overhead + 4.0us work; the work term
// matches the memory roofline (~29 MB traffic / 6.9 TB/s measured BW = 4.2us).
// Structure:
//  - 32 lanes per position, one float4 (16B) per lane -> 512B coalesced segs.
//  - 2 positions per thread (4 independent index loads, 2 gathers in flight).
//  - Conditional gather: t==0 lanes (~25%) issue no table read.
//  - Non-temporal output stores: output never re-read; keeps the ~12.6 MB of
//    gathered table rows L3-resident across graph replays.

typedef float f32x4 __attribute__((ext_vector_type(4)));

__global__ __launch_bounds__(256) void concept_emb_kernel(
    const float* __restrict__ proc,
    const float* __restrict__ med,
    const float* __restrict__ chart,
    const int*   __restrict__ concept,
    const int*   __restrict__ ttype,
    float*       __restrict__ out,
    int ngroups) {          // ngroups = npos/2
  int gid = blockIdx.x * blockDim.x + threadIdx.x;
  int j = gid & 31;         // float4 index within the 128-float row
  int g = gid >> 5;
  if (g >= ngroups) return;
  int pos0 = g * 2;
  int pos1 = pos0 + 1;

  // All four index loads issued independently (overlapping latency).
  int t0 = ttype[pos0];
  int t1 = ttype[pos1];
  int c0 = concept[pos0];
  int c1 = concept[pos1];

  // Branch-free table select; gather only where t != 0.
  const float* tab0 = (t0 == 2) ? med : (t0 == 3) ? chart : proc;
  const float* tab1 = (t1 == 2) ? med : (t1 == 3) ? chart : proc;

  f32x4 v0 = {0.f, 0.f, 0.f, 0.f};
  f32x4 v1 = {0.f, 0.f, 0.f, 0.f};
  if (t0 != 0) v0 = *reinterpret_cast<const f32x4*>(tab0 + (size_t)c0 * 128 + j * 4);
  if (t1 != 0) v1 = *reinterpret_cast<const f32x4*>(tab1 + (size_t)c1 * 128 + j * 4);

  // Non-temporal stores: don't pollute L2/L3 with the output.
  f32x4* o0 = reinterpret_cast<f32x4*>(out + (size_t)pos0 * 128 + j * 4);
  f32x4* o1 = reinterpret_cast<f32x4*>(out + (size_t)pos1 * 128 + j * 4);
  __builtin_nontemporal_store(v0, o0);
  __builtin_nontemporal_store(v1, o1);
}

extern "C" void kernel_launch(void* const* d_in, const int* in_sizes, int n_in,
                              void* d_out, int out_size, void* d_ws, size_t ws_size,
                              hipStream_t stream) {
  const float* proc    = (const float*)d_in[0];
  const float* med     = (const float*)d_in[1];
  const float* chart   = (const float*)d_in[2];
  const int*   concept = (const int*)d_in[3];
  const int*   ttype   = (const int*)d_in[4];
  float*       out     = (float*)d_out;

  const int npos    = in_sizes[3];        // B*S = 32768 (even)
  const int ngroups = npos / 2;           // 16384
  const int threads = 256;
  const long long total = (long long)ngroups * 32;   // 524288 threads
  const int blocks = (int)((total + threads - 1) / threads);  // 2048

  concept_emb_kernel<<<blocks, threads, 0, stream>>>(
      proc, med, chart, concept, ttype, out, ngroups);
}